// Round 2
// baseline (503.523 us; speedup 1.0000x reference)
//
#include <hip/hip_runtime.h>

#define THREADS 256
#define SCAN_CHUNK 2048

// ---------------- graph build ----------------

__global__ void init_k(float* __restrict__ deg, int* __restrict__ cursor, int N) {
    int i = blockIdx.x * blockDim.x + threadIdx.x;
    if (i < N) { deg[i] = 1.0f; cursor[i] = 0; }
}

__global__ void count_k(const int* __restrict__ dst, int E, float* __restrict__ deg) {
    int e = blockIdx.x * blockDim.x + threadIdx.x;
    if (e < E) atomicAdd(&deg[dst[e]], 1.0f);
}

__global__ void scan1_k(const float* __restrict__ deg, int N, int* __restrict__ blocksums) {
    __shared__ int sdata[THREADS];
    int base = blockIdx.x * SCAN_CHUNK;
    int sum = 0;
    for (int i = threadIdx.x; i < SCAN_CHUNK; i += THREADS) {
        int idx = base + i;
        if (idx < N) sum += (int)deg[idx] - 1;
    }
    sdata[threadIdx.x] = sum;
    __syncthreads();
    for (int s = THREADS / 2; s > 0; s >>= 1) {
        if (threadIdx.x < s) sdata[threadIdx.x] += sdata[threadIdx.x + s];
        __syncthreads();
    }
    if (threadIdx.x == 0) blocksums[blockIdx.x] = sdata[0];
}

__global__ void scan2_k(int* __restrict__ blocksums, int nb, int* __restrict__ rowptr,
                        int N, int E) {
    __shared__ int s[THREADS];
    int t = threadIdx.x;
    int v = (t < nb) ? blocksums[t] : 0;
    s[t] = v;
    __syncthreads();
    for (int off = 1; off < THREADS; off <<= 1) {
        int x = (t >= off) ? s[t - off] : 0;
        __syncthreads();
        s[t] += x;
        __syncthreads();
    }
    if (t < nb) blocksums[t] = s[t] - v;  // exclusive
    if (t == 0) rowptr[N] = E;
}

__global__ void scan3_k(const float* __restrict__ deg, int N,
                        const int* __restrict__ blocksums, int* __restrict__ rowptr) {
    __shared__ int s[THREADS];
    int base = blockIdx.x * SCAN_CHUNK;
    int t = threadIdx.x;
    int loc[8];
    int sum = 0;
#pragma unroll
    for (int i = 0; i < 8; ++i) {
        int idx = base + t * 8 + i;
        int c = (idx < N) ? ((int)deg[idx] - 1) : 0;
        loc[i] = sum;
        sum += c;
    }
    s[t] = sum;
    __syncthreads();
    int inc = sum;
    for (int off = 1; off < THREADS; off <<= 1) {
        int x = (t >= off) ? s[t - off] : 0;
        __syncthreads();
        s[t] += x;
        __syncthreads();
    }
    int toff = s[t] - inc + blocksums[blockIdx.x];
#pragma unroll
    for (int i = 0; i < 8; ++i) {
        int idx = base + t * 8 + i;
        if (idx < N) rowptr[idx] = toff + loc[i];
    }
}

__global__ void rsqrt_k(float* __restrict__ deg, int N) {
    int i = blockIdx.x * blockDim.x + threadIdx.x;
    if (i < N) deg[i] = rsqrtf(deg[i]);
}

__global__ void scatter_k(const int* __restrict__ src, const int* __restrict__ dst, int E,
                          const int* __restrict__ rowptr, int* __restrict__ cursor,
                          int* __restrict__ csr) {
    int e = blockIdx.x * blockDim.x + threadIdx.x;
    if (e >= E) return;
    int t = dst[e];
    int pos = rowptr[t] + atomicAdd(&cursor[t], 1);
    csr[pos] = src[e];
}

// ---------------- fp32 GEMM: C[N x OUTC] = A[N x 128] * W[128 x OUTC] ----------------

template <int OUTC>
__global__ __launch_bounds__(256) void gemm_k128(const float* __restrict__ A,
                                                 const float* __restrict__ W,
                                                 float* __restrict__ C, int N) {
    constexpr int KT = 32;
    constexpr int CP4 = OUTC / 64;  // float4s per thread: 2 (OUTC=128) or 1 (OUTC=64)
    __shared__ float As[64][KT + 1];       // +1 pad: conflict-free row broadcasts
    __shared__ float Ws[KT * OUTC];

    int tid = threadIdx.x;
    int tx = tid & 15;        // 16 col-groups
    int ty = tid >> 4;        // 16 row-threads
    int row0 = blockIdx.x * 64;

    float4 acc[4][CP4];
#pragma unroll
    for (int r = 0; r < 4; ++r)
#pragma unroll
        for (int c = 0; c < CP4; ++c) acc[r][c] = make_float4(0.f, 0.f, 0.f, 0.f);

    int sr = tid >> 2;             // 0..63 staging row
    int skb = (tid & 3) * 8;       // 0,8,16,24 staging k-base

    for (int kk = 0; kk < 128; kk += KT) {
        // stage A tile (64 x 32)
        int gr = row0 + sr;
        if (gr > N - 1) gr = N - 1;
        const float* ap = A + (size_t)gr * 128 + kk + skb;
        float4 av0 = *(const float4*)ap;
        float4 av1 = *(const float4*)(ap + 4);
        As[sr][skb + 0] = av0.x; As[sr][skb + 1] = av0.y;
        As[sr][skb + 2] = av0.z; As[sr][skb + 3] = av0.w;
        As[sr][skb + 4] = av1.x; As[sr][skb + 5] = av1.y;
        As[sr][skb + 6] = av1.z; As[sr][skb + 7] = av1.w;
        // stage W tile (32 x OUTC, contiguous in global)
        const float4* wsrc = (const float4*)(W + (size_t)kk * OUTC);
        float4* wdst = (float4*)Ws;
        for (int i = tid; i < KT * OUTC / 4; i += 256) wdst[i] = wsrc[i];
        __syncthreads();

#pragma unroll 8
        for (int k = 0; k < KT; ++k) {
            float a0 = As[ty][k];
            float a1 = As[ty + 16][k];
            float a2 = As[ty + 32][k];
            float a3 = As[ty + 48][k];
            const float4* wrow = (const float4*)&Ws[k * OUTC];
#pragma unroll
            for (int c = 0; c < CP4; ++c) {
                float4 w = wrow[tx * CP4 + c];
                acc[0][c].x = fmaf(a0, w.x, acc[0][c].x);
                acc[0][c].y = fmaf(a0, w.y, acc[0][c].y);
                acc[0][c].z = fmaf(a0, w.z, acc[0][c].z);
                acc[0][c].w = fmaf(a0, w.w, acc[0][c].w);
                acc[1][c].x = fmaf(a1, w.x, acc[1][c].x);
                acc[1][c].y = fmaf(a1, w.y, acc[1][c].y);
                acc[1][c].z = fmaf(a1, w.z, acc[1][c].z);
                acc[1][c].w = fmaf(a1, w.w, acc[1][c].w);
                acc[2][c].x = fmaf(a2, w.x, acc[2][c].x);
                acc[2][c].y = fmaf(a2, w.y, acc[2][c].y);
                acc[2][c].z = fmaf(a2, w.z, acc[2][c].z);
                acc[2][c].w = fmaf(a2, w.w, acc[2][c].w);
                acc[3][c].x = fmaf(a3, w.x, acc[3][c].x);
                acc[3][c].y = fmaf(a3, w.y, acc[3][c].y);
                acc[3][c].z = fmaf(a3, w.z, acc[3][c].z);
                acc[3][c].w = fmaf(a3, w.w, acc[3][c].w);
            }
        }
        __syncthreads();
    }

#pragma unroll
    for (int rr = 0; rr < 4; ++rr) {
        int r = row0 + ty + rr * 16;
        if (r < N) {
            float4* cp = (float4*)(C + (size_t)r * OUTC);
#pragma unroll
            for (int c = 0; c < CP4; ++c) cp[tx * CP4 + c] = acc[rr][c];
        }
    }
}

// ---------------- aggregation: out[i] = dinv[i]*(dinv[i]*h[i] + sum_j dinv[j]*h[j]) + b ----

template <int C, bool RELU>
__global__ __launch_bounds__(256) void aggregate_k(const float* __restrict__ h,
                                                   const float* __restrict__ dinv,
                                                   const int* __restrict__ rowptr,
                                                   const int* __restrict__ csr,
                                                   const float* __restrict__ bias,
                                                   float* __restrict__ out, int N) {
    constexpr int LANES = C / 4;
    constexpr int NPB = 256 / LANES;
    int tid = threadIdx.x;
    int sub = tid / LANES;
    int lane = tid % LANES;
    int node = blockIdx.x * NPB + sub;
    if (node >= N) return;

    const float4* h4 = (const float4*)h;
    float di = dinv[node];
    float4 hv = h4[(size_t)node * LANES + lane];
    float4 acc;
    acc.x = di * hv.x; acc.y = di * hv.y; acc.z = di * hv.z; acc.w = di * hv.w;

    int beg = rowptr[node];
    int end = rowptr[node + 1];
    for (int e = beg; e < end; ++e) {
        int j = csr[e];
        float wj = dinv[j];
        float4 hj = h4[(size_t)j * LANES + lane];
        acc.x = fmaf(wj, hj.x, acc.x);
        acc.y = fmaf(wj, hj.y, acc.y);
        acc.z = fmaf(wj, hj.z, acc.z);
        acc.w = fmaf(wj, hj.w, acc.w);
    }

    float4 bv = ((const float4*)bias)[lane];
    float4 o;
    o.x = fmaf(di, acc.x, bv.x);
    o.y = fmaf(di, acc.y, bv.y);
    o.z = fmaf(di, acc.z, bv.z);
    o.w = fmaf(di, acc.w, bv.w);
    if (RELU) {
        o.x = fmaxf(o.x, 0.f); o.y = fmaxf(o.y, 0.f);
        o.z = fmaxf(o.z, 0.f); o.w = fmaxf(o.w, 0.f);
    }
    ((float4*)out)[(size_t)node * LANES + lane] = o;
}

// ---------------- launch ----------------

extern "C" void kernel_launch(void* const* d_in, const int* in_sizes, int n_in,
                              void* d_out, int out_size, void* d_ws, size_t ws_size,
                              hipStream_t stream) {
    const float* x  = (const float*)d_in[0];
    const int*   ei = (const int*)d_in[1];
    const float* W1 = (const float*)d_in[2];
    const float* b1 = (const float*)d_in[3];
    const float* W2 = (const float*)d_in[4];
    const float* b2 = (const float*)d_in[5];
    float* out = (float*)d_out;

    const int D = 128;
    int N = in_sizes[0] / D;
    int E = in_sizes[1] / 2;
    const int* src = ei;      // edge_index[0] (sources j)
    const int* dst = ei + E;  // edge_index[1] (targets i)

    char* ws = (char*)d_ws;
    size_t off = 0;
    auto alloc = [&](size_t bytes) -> void* {
        void* p = ws + off;
        off += (bytes + 255) & ~(size_t)255;
        return p;
    };
    float* deg   = (float*)alloc((size_t)N * 4);        // becomes dinv after rsqrt_k
    int*   rowptr= (int*)alloc((size_t)(N + 1) * 4);
    int*   cursor= (int*)alloc((size_t)N * 4);
    int*   bsums = (int*)alloc(1024);
    int*   csr   = (int*)alloc((size_t)E * 4);
    float* h1    = (float*)alloc((size_t)N * 128 * 4);
    float* h1a   = (float*)alloc((size_t)N * 128 * 4);
    float* h2    = h1;  // reuse (N*64 <= N*128)

    int gN = (N + THREADS - 1) / THREADS;
    int gE = (E + THREADS - 1) / THREADS;
    int NB1 = (N + SCAN_CHUNK - 1) / SCAN_CHUNK;

    init_k<<<gN, THREADS, 0, stream>>>(deg, cursor, N);
    count_k<<<gE, THREADS, 0, stream>>>(dst, E, deg);
    scan1_k<<<NB1, THREADS, 0, stream>>>(deg, N, bsums);
    scan2_k<<<1, THREADS, 0, stream>>>(bsums, NB1, rowptr, N, E);
    scan3_k<<<NB1, THREADS, 0, stream>>>(deg, N, bsums, rowptr);
    rsqrt_k<<<gN, THREADS, 0, stream>>>(deg, N);
    scatter_k<<<gE, THREADS, 0, stream>>>(src, dst, E, rowptr, cursor, csr);

    // layer 1
    gemm_k128<128><<<(N + 63) / 64, 256, 0, stream>>>(x, W1, h1, N);
    aggregate_k<128, true><<<(N + 7) / 8, 256, 0, stream>>>(h1, deg, rowptr, csr, b1, h1a, N);
    // layer 2
    gemm_k128<64><<<(N + 63) / 64, 256, 0, stream>>>(h1a, W2, h2, N);
    aggregate_k<64, false><<<(N + 15) / 16, 256, 0, stream>>>(h2, deg, rowptr, csr, b2, out, N);
}

// Round 3
// 482.699 us; speedup vs baseline: 1.0431x; 1.0431x over previous
//
#include <hip/hip_runtime.h>

#define THREADS 256
#define SCAN_CHUNK 2048

// ---------------- graph build ----------------

__global__ void init_k(float* __restrict__ deg, int* __restrict__ cursor, int N) {
    int i = blockIdx.x * blockDim.x + threadIdx.x;
    if (i < N) { deg[i] = 1.0f; cursor[i] = 0; }
}

__global__ void count_k(const int* __restrict__ dst, int E, float* __restrict__ deg) {
    int e = blockIdx.x * blockDim.x + threadIdx.x;
    if (e < E) atomicAdd(&deg[dst[e]], 1.0f);
}

__global__ void scan1_k(const float* __restrict__ deg, int N, int* __restrict__ blocksums) {
    __shared__ int sdata[THREADS];
    int base = blockIdx.x * SCAN_CHUNK;
    int sum = 0;
    for (int i = threadIdx.x; i < SCAN_CHUNK; i += THREADS) {
        int idx = base + i;
        if (idx < N) sum += (int)deg[idx] - 1;
    }
    sdata[threadIdx.x] = sum;
    __syncthreads();
    for (int s = THREADS / 2; s > 0; s >>= 1) {
        if (threadIdx.x < s) sdata[threadIdx.x] += sdata[threadIdx.x + s];
        __syncthreads();
    }
    if (threadIdx.x == 0) blocksums[blockIdx.x] = sdata[0];
}

__global__ void scan2_k(int* __restrict__ blocksums, int nb, int* __restrict__ rowptr,
                        int N, int E) {
    __shared__ int s[THREADS];
    int t = threadIdx.x;
    int v = (t < nb) ? blocksums[t] : 0;
    s[t] = v;
    __syncthreads();
    for (int off = 1; off < THREADS; off <<= 1) {
        int x = (t >= off) ? s[t - off] : 0;
        __syncthreads();
        s[t] += x;
        __syncthreads();
    }
    if (t < nb) blocksums[t] = s[t] - v;  // exclusive
    if (t == 0) rowptr[N] = E;
}

__global__ void scan3_k(const float* __restrict__ deg, int N,
                        const int* __restrict__ blocksums, int* __restrict__ rowptr) {
    __shared__ int s[THREADS];
    int base = blockIdx.x * SCAN_CHUNK;
    int t = threadIdx.x;
    int loc[8];
    int sum = 0;
#pragma unroll
    for (int i = 0; i < 8; ++i) {
        int idx = base + t * 8 + i;
        int c = (idx < N) ? ((int)deg[idx] - 1) : 0;
        loc[i] = sum;
        sum += c;
    }
    s[t] = sum;
    __syncthreads();
    int inc = sum;
    for (int off = 1; off < THREADS; off <<= 1) {
        int x = (t >= off) ? s[t - off] : 0;
        __syncthreads();
        s[t] += x;
        __syncthreads();
    }
    int toff = s[t] - inc + blocksums[blockIdx.x];
#pragma unroll
    for (int i = 0; i < 8; ++i) {
        int idx = base + t * 8 + i;
        if (idx < N) rowptr[idx] = toff + loc[i];
    }
}

__global__ void rsqrt_k(float* __restrict__ deg, int N) {
    int i = blockIdx.x * blockDim.x + threadIdx.x;
    if (i < N) deg[i] = rsqrtf(deg[i]);
}

__global__ void scatter_k(const int* __restrict__ src, const int* __restrict__ dst, int E,
                          const int* __restrict__ rowptr, int* __restrict__ cursor,
                          int* __restrict__ csr) {
    int e = blockIdx.x * blockDim.x + threadIdx.x;
    if (e >= E) return;
    int t = dst[e];
    int pos = rowptr[t] + atomicAdd(&cursor[t], 1);
    csr[pos] = src[e];
}

// ---------------- fp32 GEMM: C[N x OUTC] = dinv[row] * (A[N x 128] * W[128 x OUTC]) ----

template <int OUTC>
__global__ __launch_bounds__(256) void gemm_k128(const float* __restrict__ A,
                                                 const float* __restrict__ W,
                                                 const float* __restrict__ dinv,
                                                 float* __restrict__ C, int N) {
    constexpr int KT = 32;
    constexpr int CP4 = OUTC / 64;  // float4s per thread: 2 (OUTC=128) or 1 (OUTC=64)
    __shared__ float As[64][KT + 1];       // +1 pad: conflict-free row broadcasts
    __shared__ float Ws[KT * OUTC];

    int tid = threadIdx.x;
    int tx = tid & 15;        // 16 col-groups
    int ty = tid >> 4;        // 16 row-threads
    int row0 = blockIdx.x * 64;

    float4 acc[4][CP4];
#pragma unroll
    for (int r = 0; r < 4; ++r)
#pragma unroll
        for (int c = 0; c < CP4; ++c) acc[r][c] = make_float4(0.f, 0.f, 0.f, 0.f);

    int sr = tid >> 2;             // 0..63 staging row
    int skb = (tid & 3) * 8;       // 0,8,16,24 staging k-base

    for (int kk = 0; kk < 128; kk += KT) {
        // stage A tile (64 x 32)
        int gr = row0 + sr;
        if (gr > N - 1) gr = N - 1;
        const float* ap = A + (size_t)gr * 128 + kk + skb;
        float4 av0 = *(const float4*)ap;
        float4 av1 = *(const float4*)(ap + 4);
        As[sr][skb + 0] = av0.x; As[sr][skb + 1] = av0.y;
        As[sr][skb + 2] = av0.z; As[sr][skb + 3] = av0.w;
        As[sr][skb + 4] = av1.x; As[sr][skb + 5] = av1.y;
        As[sr][skb + 6] = av1.z; As[sr][skb + 7] = av1.w;
        // stage W tile (32 x OUTC, contiguous in global)
        const float4* wsrc = (const float4*)(W + (size_t)kk * OUTC);
        float4* wdst = (float4*)Ws;
        for (int i = tid; i < KT * OUTC / 4; i += 256) wdst[i] = wsrc[i];
        __syncthreads();

#pragma unroll 8
        for (int k = 0; k < KT; ++k) {
            float a0 = As[ty][k];
            float a1 = As[ty + 16][k];
            float a2 = As[ty + 32][k];
            float a3 = As[ty + 48][k];
            const float4* wrow = (const float4*)&Ws[k * OUTC];
#pragma unroll
            for (int c = 0; c < CP4; ++c) {
                float4 w = wrow[tx * CP4 + c];
                acc[0][c].x = fmaf(a0, w.x, acc[0][c].x);
                acc[0][c].y = fmaf(a0, w.y, acc[0][c].y);
                acc[0][c].z = fmaf(a0, w.z, acc[0][c].z);
                acc[0][c].w = fmaf(a0, w.w, acc[0][c].w);
                acc[1][c].x = fmaf(a1, w.x, acc[1][c].x);
                acc[1][c].y = fmaf(a1, w.y, acc[1][c].y);
                acc[1][c].z = fmaf(a1, w.z, acc[1][c].z);
                acc[1][c].w = fmaf(a1, w.w, acc[1][c].w);
                acc[2][c].x = fmaf(a2, w.x, acc[2][c].x);
                acc[2][c].y = fmaf(a2, w.y, acc[2][c].y);
                acc[2][c].z = fmaf(a2, w.z, acc[2][c].z);
                acc[2][c].w = fmaf(a2, w.w, acc[2][c].w);
                acc[3][c].x = fmaf(a3, w.x, acc[3][c].x);
                acc[3][c].y = fmaf(a3, w.y, acc[3][c].y);
                acc[3][c].z = fmaf(a3, w.z, acc[3][c].z);
                acc[3][c].w = fmaf(a3, w.w, acc[3][c].w);
            }
        }
        __syncthreads();
    }

#pragma unroll
    for (int rr = 0; rr < 4; ++rr) {
        int r = row0 + ty + rr * 16;
        if (r < N) {
            float dr = dinv[r];   // pre-scale: hs[r] = dinv[r] * (A@W)[r]
            float4* cp = (float4*)(C + (size_t)r * OUTC);
#pragma unroll
            for (int c = 0; c < CP4; ++c) {
                float4 v = acc[rr][c];
                v.x *= dr; v.y *= dr; v.z *= dr; v.w *= dr;
                cp[tx * CP4 + c] = v;
            }
        }
    }
}

// ---- aggregation: out[i] = dinv[i]*(hs[i] + sum_{j in N(i)} hs[j]) + b, hs pre-scaled ----

template <int C, bool RELU>
__global__ __launch_bounds__(256) void aggregate_k(const float* __restrict__ hs,
                                                   const float* __restrict__ dinv,
                                                   const int* __restrict__ rowptr,
                                                   const int* __restrict__ csr,
                                                   const float* __restrict__ bias,
                                                   float* __restrict__ out, int N) {
    constexpr int LANES = C / 4;
    constexpr int NPB = 256 / LANES;
    int tid = threadIdx.x;
    int sub = tid / LANES;
    int lane = tid % LANES;
    int node = blockIdx.x * NPB + sub;
    if (node >= N) return;

    const float4* h4 = (const float4*)hs;
    // self term (hs already dinv-scaled)
    float4 acc0 = h4[(size_t)node * LANES + lane];
    float4 acc1 = make_float4(0.f, 0.f, 0.f, 0.f);

    int beg = rowptr[node];
    int end = rowptr[node + 1];
    int e = beg;
    // 4-deep pipelined gather: 4 independent index loads, then 4 independent row loads
    for (; e + 4 <= end; e += 4) {
        int j0 = csr[e + 0];
        int j1 = csr[e + 1];
        int j2 = csr[e + 2];
        int j3 = csr[e + 3];
        float4 v0 = h4[(size_t)j0 * LANES + lane];
        float4 v1 = h4[(size_t)j1 * LANES + lane];
        float4 v2 = h4[(size_t)j2 * LANES + lane];
        float4 v3 = h4[(size_t)j3 * LANES + lane];
        acc0.x += v0.x + v2.x; acc0.y += v0.y + v2.y;
        acc0.z += v0.z + v2.z; acc0.w += v0.w + v2.w;
        acc1.x += v1.x + v3.x; acc1.y += v1.y + v3.y;
        acc1.z += v1.z + v3.z; acc1.w += v1.w + v3.w;
    }
    for (; e < end; ++e) {
        int j = csr[e];
        float4 v = h4[(size_t)j * LANES + lane];
        acc0.x += v.x; acc0.y += v.y; acc0.z += v.z; acc0.w += v.w;
    }

    float di = dinv[node];
    float4 bv = ((const float4*)bias)[lane];
    float4 o;
    o.x = fmaf(di, acc0.x + acc1.x, bv.x);
    o.y = fmaf(di, acc0.y + acc1.y, bv.y);
    o.z = fmaf(di, acc0.z + acc1.z, bv.z);
    o.w = fmaf(di, acc0.w + acc1.w, bv.w);
    if (RELU) {
        o.x = fmaxf(o.x, 0.f); o.y = fmaxf(o.y, 0.f);
        o.z = fmaxf(o.z, 0.f); o.w = fmaxf(o.w, 0.f);
    }
    ((float4*)out)[(size_t)node * LANES + lane] = o;
}

// ---------------- launch ----------------

extern "C" void kernel_launch(void* const* d_in, const int* in_sizes, int n_in,
                              void* d_out, int out_size, void* d_ws, size_t ws_size,
                              hipStream_t stream) {
    const float* x  = (const float*)d_in[0];
    const int*   ei = (const int*)d_in[1];
    const float* W1 = (const float*)d_in[2];
    const float* b1 = (const float*)d_in[3];
    const float* W2 = (const float*)d_in[4];
    const float* b2 = (const float*)d_in[5];
    float* out = (float*)d_out;

    const int D = 128;
    int N = in_sizes[0] / D;
    int E = in_sizes[1] / 2;
    const int* src = ei;      // edge_index[0] (sources j)
    const int* dst = ei + E;  // edge_index[1] (targets i)

    char* ws = (char*)d_ws;
    size_t off = 0;
    auto alloc = [&](size_t bytes) -> void* {
        void* p = ws + off;
        off += (bytes + 255) & ~(size_t)255;
        return p;
    };
    float* deg   = (float*)alloc((size_t)N * 4);        // becomes dinv after rsqrt_k
    int*   rowptr= (int*)alloc((size_t)(N + 1) * 4);
    int*   cursor= (int*)alloc((size_t)N * 4);
    int*   bsums = (int*)alloc(1024);
    int*   csr   = (int*)alloc((size_t)E * 4);
    float* h1    = (float*)alloc((size_t)N * 128 * 4);  // hs1 = dinv * (x@W1)
    float* h1a   = (float*)alloc((size_t)N * 128 * 4);  // layer-1 output
    float* h2    = h1;  // reuse (N*64 <= N*128): hs2 = dinv * (h1a@W2)

    int gN = (N + THREADS - 1) / THREADS;
    int gE = (E + THREADS - 1) / THREADS;
    int NB1 = (N + SCAN_CHUNK - 1) / SCAN_CHUNK;

    init_k<<<gN, THREADS, 0, stream>>>(deg, cursor, N);
    count_k<<<gE, THREADS, 0, stream>>>(dst, E, deg);
    scan1_k<<<NB1, THREADS, 0, stream>>>(deg, N, bsums);
    scan2_k<<<1, THREADS, 0, stream>>>(bsums, NB1, rowptr, N, E);
    scan3_k<<<NB1, THREADS, 0, stream>>>(deg, N, bsums, rowptr);
    rsqrt_k<<<gN, THREADS, 0, stream>>>(deg, N);
    scatter_k<<<gE, THREADS, 0, stream>>>(src, dst, E, rowptr, cursor, csr);

    // layer 1
    gemm_k128<128><<<(N + 63) / 64, 256, 0, stream>>>(x, W1, deg, h1, N);
    aggregate_k<128, true><<<(N + 7) / 8, 256, 0, stream>>>(h1, deg, rowptr, csr, b1, h1a, N);
    // layer 2
    gemm_k128<64><<<(N + 63) / 64, 256, 0, stream>>>(h1a, W2, deg, h2, N);
    aggregate_k<64, false><<<(N + 15) / 16, 256, 0, stream>>>(h2, deg, rowptr, csr, b2, out, N);
}

// Round 4
// 300.933 us; speedup vs baseline: 1.6732x; 1.6040x over previous
//
#include <hip/hip_runtime.h>

#define THREADS 256
#define SCAN_CHUNK 2048

typedef unsigned int uint;
typedef unsigned short ushort;

// ---------------- bf16 helpers ----------------

__device__ __forceinline__ uint f2bf(float f) {       // RNE round to bf16, return in low 16
    uint b = __float_as_uint(f);
    return (b + 0x7fffu + ((b >> 16) & 1u)) >> 16;
}
__device__ __forceinline__ uint pack2(float a, float b) {
    return f2bf(a) | (f2bf(b) << 16);
}
__device__ __forceinline__ float bflo(uint u) { return __uint_as_float(u << 16); }
__device__ __forceinline__ float bfhi(uint u) { return __uint_as_float(u & 0xffff0000u); }

// ---------------- graph build ----------------

__global__ void init_k(int* __restrict__ cnt, int N) {
    int i = blockIdx.x * blockDim.x + threadIdx.x;
    if (i < N) cnt[i] = 0;
}

// one atomic pass: per-edge rank within its target + final counts
__global__ void rank_k(const int* __restrict__ dst, int E, int half,
                       int* __restrict__ cnt, int* __restrict__ rank) {
    int i = blockIdx.x * blockDim.x + threadIdx.x;
    if (i >= half) return;
    int e1 = i + half;
    int t0 = dst[i];
    int t1 = (e1 < E) ? dst[e1] : 0;
    int r0 = atomicAdd(&cnt[t0], 1);
    int r1 = (e1 < E) ? atomicAdd(&cnt[t1], 1) : 0;
    rank[i] = r0;
    if (e1 < E) rank[e1] = r1;
}

__global__ void scan1_k(const int* __restrict__ cnt, int N, int* __restrict__ blocksums) {
    __shared__ int sdata[THREADS];
    int base = blockIdx.x * SCAN_CHUNK;
    int sum = 0;
    for (int i = threadIdx.x; i < SCAN_CHUNK; i += THREADS) {
        int idx = base + i;
        if (idx < N) sum += cnt[idx];
    }
    sdata[threadIdx.x] = sum;
    __syncthreads();
    for (int s = THREADS / 2; s > 0; s >>= 1) {
        if (threadIdx.x < s) sdata[threadIdx.x] += sdata[threadIdx.x + s];
        __syncthreads();
    }
    if (threadIdx.x == 0) blocksums[blockIdx.x] = sdata[0];
}

__global__ void scan2_k(int* __restrict__ blocksums, int nb, int* __restrict__ rowptr,
                        int N, int E) {
    __shared__ int s[THREADS];
    int t = threadIdx.x;
    int v = (t < nb) ? blocksums[t] : 0;
    s[t] = v;
    __syncthreads();
    for (int off = 1; off < THREADS; off <<= 1) {
        int x = (t >= off) ? s[t - off] : 0;
        __syncthreads();
        s[t] += x;
        __syncthreads();
    }
    if (t < nb) blocksums[t] = s[t] - v;  // exclusive
    if (t == 0) rowptr[N] = E;
}

__global__ void scan3_k(const int* __restrict__ cnt, int N,
                        const int* __restrict__ blocksums, int* __restrict__ rowptr) {
    __shared__ int s[THREADS];
    int base = blockIdx.x * SCAN_CHUNK;
    int t = threadIdx.x;
    int loc[8];
    int sum = 0;
#pragma unroll
    for (int i = 0; i < 8; ++i) {
        int idx = base + t * 8 + i;
        int c = (idx < N) ? cnt[idx] : 0;
        loc[i] = sum;
        sum += c;
    }
    s[t] = sum;
    __syncthreads();
    int inc = sum;
    for (int off = 1; off < THREADS; off <<= 1) {
        int x = (t >= off) ? s[t - off] : 0;
        __syncthreads();
        s[t] += x;
        __syncthreads();
    }
    int toff = s[t] - inc + blocksums[blockIdx.x];
#pragma unroll
    for (int i = 0; i < 8; ++i) {
        int idx = base + t * 8 + i;
        if (idx < N) rowptr[idx] = toff + loc[i];
    }
}

__global__ void dinv_k(const int* __restrict__ cnt, float* __restrict__ dinv, int N) {
    int i = blockIdx.x * blockDim.x + threadIdx.x;
    if (i < N) dinv[i] = rsqrtf((float)(1 + cnt[i]));
}

// atomic-free CSR fill: rowptr is L2-resident (400KB), only the csr write is random
__global__ void scatter2_k(const int* __restrict__ src, const int* __restrict__ dst,
                           int E, int half, const int* __restrict__ rowptr,
                           const int* __restrict__ rank, int* __restrict__ csr) {
    int i = blockIdx.x * blockDim.x + threadIdx.x;
    if (i >= half) return;
    int e1 = i + half;
    int t0 = dst[i];
    int s0 = src[i];
    int r0 = rank[i];
    int t1 = (e1 < E) ? dst[e1] : 0;
    int s1 = (e1 < E) ? src[e1] : 0;
    int r1 = (e1 < E) ? rank[e1] : 0;
    int p0 = rowptr[t0];
    int p1 = rowptr[t1];
    csr[p0 + r0] = s0;
    if (e1 < E) csr[p1 + r1] = s1;
}

// ---- fp32 GEMM: hs[N x OUTC] (bf16) = dinv[row] * (A[N x 128] * W[128 x OUTC]) ----

template <int OUTC>
__global__ __launch_bounds__(256) void gemm_k128(const float* __restrict__ A,
                                                 const float* __restrict__ W,
                                                 const float* __restrict__ dinv,
                                                 ushort* __restrict__ hs, int N) {
    constexpr int KT = 32;
    constexpr int CP4 = OUTC / 64;  // float4s per thread: 2 (OUTC=128) or 1 (OUTC=64)
    __shared__ float As[64][KT + 1];
    __shared__ float Ws[KT * OUTC];

    int tid = threadIdx.x;
    int tx = tid & 15;
    int ty = tid >> 4;
    int row0 = blockIdx.x * 64;

    float4 acc[4][CP4];
#pragma unroll
    for (int r = 0; r < 4; ++r)
#pragma unroll
        for (int c = 0; c < CP4; ++c) acc[r][c] = make_float4(0.f, 0.f, 0.f, 0.f);

    int sr = tid >> 2;
    int skb = (tid & 3) * 8;

    for (int kk = 0; kk < 128; kk += KT) {
        int gr = row0 + sr;
        if (gr > N - 1) gr = N - 1;
        const float* ap = A + (size_t)gr * 128 + kk + skb;
        float4 av0 = *(const float4*)ap;
        float4 av1 = *(const float4*)(ap + 4);
        As[sr][skb + 0] = av0.x; As[sr][skb + 1] = av0.y;
        As[sr][skb + 2] = av0.z; As[sr][skb + 3] = av0.w;
        As[sr][skb + 4] = av1.x; As[sr][skb + 5] = av1.y;
        As[sr][skb + 6] = av1.z; As[sr][skb + 7] = av1.w;
        const float4* wsrc = (const float4*)(W + (size_t)kk * OUTC);
        float4* wdst = (float4*)Ws;
        for (int i = tid; i < KT * OUTC / 4; i += 256) wdst[i] = wsrc[i];
        __syncthreads();

#pragma unroll 8
        for (int k = 0; k < KT; ++k) {
            float a0 = As[ty][k];
            float a1 = As[ty + 16][k];
            float a2 = As[ty + 32][k];
            float a3 = As[ty + 48][k];
            const float4* wrow = (const float4*)&Ws[k * OUTC];
#pragma unroll
            for (int c = 0; c < CP4; ++c) {
                float4 w = wrow[tx * CP4 + c];
                acc[0][c].x = fmaf(a0, w.x, acc[0][c].x);
                acc[0][c].y = fmaf(a0, w.y, acc[0][c].y);
                acc[0][c].z = fmaf(a0, w.z, acc[0][c].z);
                acc[0][c].w = fmaf(a0, w.w, acc[0][c].w);
                acc[1][c].x = fmaf(a1, w.x, acc[1][c].x);
                acc[1][c].y = fmaf(a1, w.y, acc[1][c].y);
                acc[1][c].z = fmaf(a1, w.z, acc[1][c].z);
                acc[1][c].w = fmaf(a1, w.w, acc[1][c].w);
                acc[2][c].x = fmaf(a2, w.x, acc[2][c].x);
                acc[2][c].y = fmaf(a2, w.y, acc[2][c].y);
                acc[2][c].z = fmaf(a2, w.z, acc[2][c].z);
                acc[2][c].w = fmaf(a2, w.w, acc[2][c].w);
                acc[3][c].x = fmaf(a3, w.x, acc[3][c].x);
                acc[3][c].y = fmaf(a3, w.y, acc[3][c].y);
                acc[3][c].z = fmaf(a3, w.z, acc[3][c].z);
                acc[3][c].w = fmaf(a3, w.w, acc[3][c].w);
            }
        }
        __syncthreads();
    }

#pragma unroll
    for (int rr = 0; rr < 4; ++rr) {
        int r = row0 + ty + rr * 16;
        if (r < N) {
            float dr = dinv[r];   // pre-scale: hs[r] = bf16(dinv[r] * (A@W)[r])
            uint2* cp = (uint2*)(hs + (size_t)r * OUTC);
#pragma unroll
            for (int c = 0; c < CP4; ++c) {
                float4 v = acc[rr][c];
                uint2 p;
                p.x = pack2(v.x * dr, v.y * dr);
                p.y = pack2(v.z * dr, v.w * dr);
                cp[tx * CP4 + c] = p;
            }
        }
    }
}

// ---- aggregation (bf16 gather, f32 accum):
//      out[i] = dinv[i]*(hs[i] + sum_{j in N(i)} hs[j]) + b ----

template <int C, bool RELU>
__global__ __launch_bounds__(256) void aggregate_k(const ushort* __restrict__ hs,
                                                   const float* __restrict__ dinv,
                                                   const int* __restrict__ rowptr,
                                                   const int* __restrict__ csr,
                                                   const float* __restrict__ bias,
                                                   float* __restrict__ out, int N) {
    constexpr int LANES = C / 8;       // lanes per node, 16B (8 bf16) per lane
    constexpr int NPB = 256 / LANES;
    int tid = threadIdx.x;
    int sub = tid / LANES;
    int lane = tid % LANES;
    int node = blockIdx.x * NPB + sub;
    if (node >= N) return;

    const uint4* h4 = (const uint4*)hs;   // one uint4 = 8 bf16
    float accA[8], accB[8];
    {   // self term
        uint4 v = h4[(size_t)node * LANES + lane];
        accA[0] = bflo(v.x); accA[1] = bfhi(v.x);
        accA[2] = bflo(v.y); accA[3] = bfhi(v.y);
        accA[4] = bflo(v.z); accA[5] = bfhi(v.z);
        accA[6] = bflo(v.w); accA[7] = bfhi(v.w);
    }
#pragma unroll
    for (int k = 0; k < 8; ++k) accB[k] = 0.f;

    int beg = rowptr[node];
    int end = rowptr[node + 1];
    int e = beg;
    for (; e + 4 <= end; e += 4) {
        int j0 = csr[e + 0];
        int j1 = csr[e + 1];
        int j2 = csr[e + 2];
        int j3 = csr[e + 3];
        uint4 v0 = h4[(size_t)j0 * LANES + lane];
        uint4 v1 = h4[(size_t)j1 * LANES + lane];
        uint4 v2 = h4[(size_t)j2 * LANES + lane];
        uint4 v3 = h4[(size_t)j3 * LANES + lane];
        accA[0] += bflo(v0.x) + bflo(v2.x); accA[1] += bfhi(v0.x) + bfhi(v2.x);
        accA[2] += bflo(v0.y) + bflo(v2.y); accA[3] += bfhi(v0.y) + bfhi(v2.y);
        accA[4] += bflo(v0.z) + bflo(v2.z); accA[5] += bfhi(v0.z) + bfhi(v2.z);
        accA[6] += bflo(v0.w) + bflo(v2.w); accA[7] += bfhi(v0.w) + bfhi(v2.w);
        accB[0] += bflo(v1.x) + bflo(v3.x); accB[1] += bfhi(v1.x) + bfhi(v3.x);
        accB[2] += bflo(v1.y) + bflo(v3.y); accB[3] += bfhi(v1.y) + bfhi(v3.y);
        accB[4] += bflo(v1.z) + bflo(v3.z); accB[5] += bfhi(v1.z) + bfhi(v3.z);
        accB[6] += bflo(v1.w) + bflo(v3.w); accB[7] += bfhi(v1.w) + bfhi(v3.w);
    }
    for (; e < end; ++e) {
        int j = csr[e];
        uint4 v = h4[(size_t)j * LANES + lane];
        accA[0] += bflo(v.x); accA[1] += bfhi(v.x);
        accA[2] += bflo(v.y); accA[3] += bfhi(v.y);
        accA[4] += bflo(v.z); accA[5] += bfhi(v.z);
        accA[6] += bflo(v.w); accA[7] += bfhi(v.w);
    }

    float di = dinv[node];
    const float4* b4 = (const float4*)(bias + lane * 8);
    float4 b0 = b4[0], b1 = b4[1];
    float4 o0, o1;
    o0.x = fmaf(di, accA[0] + accB[0], b0.x);
    o0.y = fmaf(di, accA[1] + accB[1], b0.y);
    o0.z = fmaf(di, accA[2] + accB[2], b0.z);
    o0.w = fmaf(di, accA[3] + accB[3], b0.w);
    o1.x = fmaf(di, accA[4] + accB[4], b1.x);
    o1.y = fmaf(di, accA[5] + accB[5], b1.y);
    o1.z = fmaf(di, accA[6] + accB[6], b1.z);
    o1.w = fmaf(di, accA[7] + accB[7], b1.w);
    if (RELU) {
        o0.x = fmaxf(o0.x, 0.f); o0.y = fmaxf(o0.y, 0.f);
        o0.z = fmaxf(o0.z, 0.f); o0.w = fmaxf(o0.w, 0.f);
        o1.x = fmaxf(o1.x, 0.f); o1.y = fmaxf(o1.y, 0.f);
        o1.z = fmaxf(o1.z, 0.f); o1.w = fmaxf(o1.w, 0.f);
    }
    float4* op = (float4*)(out + (size_t)node * C + lane * 8);
    op[0] = o0;
    op[1] = o1;
}

// ---------------- launch ----------------

extern "C" void kernel_launch(void* const* d_in, const int* in_sizes, int n_in,
                              void* d_out, int out_size, void* d_ws, size_t ws_size,
                              hipStream_t stream) {
    const float* x  = (const float*)d_in[0];
    const int*   ei = (const int*)d_in[1];
    const float* W1 = (const float*)d_in[2];
    const float* b1 = (const float*)d_in[3];
    const float* W2 = (const float*)d_in[4];
    const float* b2 = (const float*)d_in[5];
    float* out = (float*)d_out;

    const int D = 128;
    int N = in_sizes[0] / D;
    int E = in_sizes[1] / 2;
    const int* src = ei;      // edge_index[0] (sources j)
    const int* dst = ei + E;  // edge_index[1] (targets i)

    char* ws = (char*)d_ws;
    size_t off = 0;
    auto alloc = [&](size_t bytes) -> void* {
        void* p = ws + off;
        off += (bytes + 255) & ~(size_t)255;
        return p;
    };
    int*    cnt   = (int*)alloc((size_t)N * 4);
    float*  dinv  = (float*)alloc((size_t)N * 4);
    int*    rowptr= (int*)alloc((size_t)(N + 1) * 4);
    int*    bsums = (int*)alloc(1024);
    int*    rank  = (int*)alloc((size_t)E * 4);
    int*    csr   = (int*)alloc((size_t)E * 4);
    ushort* hs1   = (ushort*)alloc((size_t)N * 128 * 2);  // bf16 dinv*(x@W1)
    float*  h1a   = (float*)alloc((size_t)N * 128 * 4);   // layer-1 output (f32)
    ushort* hs2   = hs1;  // reuse (N*64*2 <= N*128*2)

    int gN = (N + THREADS - 1) / THREADS;
    int half = (E + 1) / 2;
    int gH = (half + THREADS - 1) / THREADS;
    int NB1 = (N + SCAN_CHUNK - 1) / SCAN_CHUNK;

    init_k<<<gN, THREADS, 0, stream>>>(cnt, N);
    rank_k<<<gH, THREADS, 0, stream>>>(dst, E, half, cnt, rank);
    scan1_k<<<NB1, THREADS, 0, stream>>>(cnt, N, bsums);
    scan2_k<<<1, THREADS, 0, stream>>>(bsums, NB1, rowptr, N, E);
    scan3_k<<<NB1, THREADS, 0, stream>>>(cnt, N, bsums, rowptr);
    dinv_k<<<gN, THREADS, 0, stream>>>(cnt, dinv, N);
    scatter2_k<<<gH, THREADS, 0, stream>>>(src, dst, E, half, rowptr, rank, csr);

    // layer 1
    gemm_k128<128><<<(N + 63) / 64, 256, 0, stream>>>(x, W1, dinv, hs1, N);
    aggregate_k<128, true><<<(N + 15) / 16, 256, 0, stream>>>(hs1, dinv, rowptr, csr, b1, h1a, N);
    // layer 2
    gemm_k128<64><<<(N + 63) / 64, 256, 0, stream>>>(h1a, W2, dinv, hs2, N);
    aggregate_k<64, false><<<(N + 31) / 32, 256, 0, stream>>>(hs2, dinv, rowptr, csr, b2, out, N);
}

// Round 5
// 253.666 us; speedup vs baseline: 1.9850x; 1.1863x over previous
//
#include <hip/hip_runtime.h>

#define THREADS 256
#define SCAN_CHUNK 2048

typedef unsigned int uint;
typedef unsigned short ushort;
typedef short s8v __attribute__((ext_vector_type(8)));   // 8 bf16 (4 VGPRs)
typedef float f4v __attribute__((ext_vector_type(4)));   // 4 f32 acc

// ---------------- bf16 helpers ----------------

__device__ __forceinline__ uint f2bf(float f) {       // RNE round to bf16, low 16
    uint b = __float_as_uint(f);
    return (b + 0x7fffu + ((b >> 16) & 1u)) >> 16;
}
__device__ __forceinline__ uint pack2(float a, float b) {
    return f2bf(a) | (f2bf(b) << 16);
}
__device__ __forceinline__ float bflo(uint u) { return __uint_as_float(u << 16); }
__device__ __forceinline__ float bfhi(uint u) { return __uint_as_float(u & 0xffff0000u); }

// ---------------- graph build ----------------

__global__ void init_k(int* __restrict__ cnt, int N) {
    int i = blockIdx.x * blockDim.x + threadIdx.x;
    if (i < N) cnt[i] = 0;
}

__global__ void rank_k(const int* __restrict__ dst, int E, int half,
                       int* __restrict__ cnt, int* __restrict__ rank) {
    int i = blockIdx.x * blockDim.x + threadIdx.x;
    if (i >= half) return;
    int e1 = i + half;
    int t0 = dst[i];
    int t1 = (e1 < E) ? dst[e1] : 0;
    int r0 = atomicAdd(&cnt[t0], 1);
    int r1 = (e1 < E) ? atomicAdd(&cnt[t1], 1) : 0;
    rank[i] = r0;
    if (e1 < E) rank[e1] = r1;
}

__global__ void scan1_k(const int* __restrict__ cnt, int N, int* __restrict__ blocksums) {
    __shared__ int sdata[THREADS];
    int base = blockIdx.x * SCAN_CHUNK;
    int sum = 0;
    for (int i = threadIdx.x; i < SCAN_CHUNK; i += THREADS) {
        int idx = base + i;
        if (idx < N) sum += cnt[idx];
    }
    sdata[threadIdx.x] = sum;
    __syncthreads();
    for (int s = THREADS / 2; s > 0; s >>= 1) {
        if (threadIdx.x < s) sdata[threadIdx.x] += sdata[threadIdx.x + s];
        __syncthreads();
    }
    if (threadIdx.x == 0) blocksums[blockIdx.x] = sdata[0];
}

__global__ void scan2_k(int* __restrict__ blocksums, int nb, int* __restrict__ rowptr,
                        int N, int E) {
    __shared__ int s[THREADS];
    int t = threadIdx.x;
    int v = (t < nb) ? blocksums[t] : 0;
    s[t] = v;
    __syncthreads();
    for (int off = 1; off < THREADS; off <<= 1) {
        int x = (t >= off) ? s[t - off] : 0;
        __syncthreads();
        s[t] += x;
        __syncthreads();
    }
    if (t < nb) blocksums[t] = s[t] - v;  // exclusive
    if (t == 0) rowptr[N] = E;
}

__global__ void scan3_k(const int* __restrict__ cnt, int N,
                        const int* __restrict__ blocksums, int* __restrict__ rowptr) {
    __shared__ int s[THREADS];
    int base = blockIdx.x * SCAN_CHUNK;
    int t = threadIdx.x;
    int loc[8];
    int sum = 0;
#pragma unroll
    for (int i = 0; i < 8; ++i) {
        int idx = base + t * 8 + i;
        int c = (idx < N) ? cnt[idx] : 0;
        loc[i] = sum;
        sum += c;
    }
    s[t] = sum;
    __syncthreads();
    int inc = sum;
    for (int off = 1; off < THREADS; off <<= 1) {
        int x = (t >= off) ? s[t - off] : 0;
        __syncthreads();
        s[t] += x;
        __syncthreads();
    }
    int toff = s[t] - inc + blocksums[blockIdx.x];
#pragma unroll
    for (int i = 0; i < 8; ++i) {
        int idx = base + t * 8 + i;
        if (idx < N) rowptr[idx] = toff + loc[i];
    }
}

__global__ void dinv_k(const int* __restrict__ cnt, float* __restrict__ dinv, int N) {
    int i = blockIdx.x * blockDim.x + threadIdx.x;
    if (i < N) dinv[i] = rsqrtf((float)(1 + cnt[i]));
}

__global__ void scatter2_k(const int* __restrict__ src, const int* __restrict__ dst,
                           int E, int half, const int* __restrict__ rowptr,
                           const int* __restrict__ rank, int* __restrict__ csr) {
    int i = blockIdx.x * blockDim.x + threadIdx.x;
    if (i >= half) return;
    int e1 = i + half;
    int t0 = dst[i];
    int s0 = src[i];
    int r0 = rank[i];
    int t1 = (e1 < E) ? dst[e1] : 0;
    int s1 = (e1 < E) ? src[e1] : 0;
    int r1 = (e1 < E) ? rank[e1] : 0;
    int p0 = rowptr[t0];
    int p1 = rowptr[t1];
    csr[p0 + r0] = s0;
    if (e1 < E) csr[p1 + r1] = s1;
}

// ---------------- W transpose+convert: W[128][OUTC] f32 -> Wt[OUTC][128] bf16 ----------------

template <int OUTC>
__global__ void wtrans_k(const float* __restrict__ W, ushort* __restrict__ Wt) {
    int c = blockIdx.x * 64 + threadIdx.x;
    if (c >= OUTC) return;
    for (int k0 = 0; k0 < 128; k0 += 8) {
        float v[8];
#pragma unroll
        for (int i = 0; i < 8; ++i) v[i] = W[(size_t)(k0 + i) * OUTC + c];
        uint4 p;
        p.x = pack2(v[0], v[1]);
        p.y = pack2(v[2], v[3]);
        p.z = pack2(v[4], v[5]);
        p.w = pack2(v[6], v[7]);
        *(uint4*)(Wt + (size_t)c * 128 + k0) = p;
    }
}

// ---------------- MFMA GEMM: hs[N x OUTC](bf16) = dinv[row] * (A[N x 128] @ W) ----------------
// Wt is the bf16-transposed W. Swapped-operand mfma: A_op = Wt rows (16 W-cols),
// B_op = A rows; D[m][n]: m = W-col = (lane>>4)*4+reg, n = A-row = lane&15.

template <int OUTC, bool AF32>
__global__ __launch_bounds__(256) void gemm_mfma(const void* __restrict__ Ain,
                                                 const ushort* __restrict__ Wt,
                                                 const float* __restrict__ dinv,
                                                 ushort* __restrict__ hs, int N) {
    constexpr int NT = OUTC / 16;          // 16-col tiles
    constexpr int LDK = 136;               // padded K stride (bf16 units): +16B/row
    __shared__ ushort Al[64 * LDK];
    __shared__ ushort Wl[OUTC * LDK];

    int tid = threadIdx.x;
    int row0 = blockIdx.x * 64;

    // stage A tile (64 rows x 128), convert to bf16 if needed
    {
        int r = tid >> 2, seg = tid & 3;   // 32 elems per thread
        int gr = row0 + r;
        if (gr > N - 1) gr = N - 1;
        ushort* dstp = &Al[r * LDK + seg * 32];
        if (AF32) {
            const float4* ap = (const float4*)((const float*)Ain + (size_t)gr * 128 + seg * 32);
#pragma unroll
            for (int i = 0; i < 4; ++i) {
                float4 f0 = ap[2 * i], f1 = ap[2 * i + 1];
                uint4 u;
                u.x = pack2(f0.x, f0.y);
                u.y = pack2(f0.z, f0.w);
                u.z = pack2(f1.x, f1.y);
                u.w = pack2(f1.z, f1.w);
                *(uint4*)(dstp + i * 8) = u;
            }
        } else {
            const uint4* ap = (const uint4*)((const ushort*)Ain + (size_t)gr * 128 + seg * 32);
#pragma unroll
            for (int i = 0; i < 4; ++i) *(uint4*)(dstp + i * 8) = ap[i];
        }
    }
    // stage Wt (OUTC x 128 bf16, dense -> padded)
    {
        const uint4* wp = (const uint4*)Wt;
        for (int idx = tid; idx < OUTC * 16; idx += 256) {
            int r = idx >> 4, c = idx & 15;
            *(uint4*)(&Wl[r * LDK + c * 8]) = wp[idx];
        }
    }
    __syncthreads();

    int w = tid >> 6;          // wave 0..3 -> A-rows 16w..16w+15
    int l = tid & 63;
    int lo = l & 15, q = l >> 4;

    f4v acc[NT];
#pragma unroll
    for (int i = 0; i < NT; ++i) acc[i] = (f4v){0.f, 0.f, 0.f, 0.f};

#pragma unroll
    for (int ks = 0; ks < 4; ++ks) {
        s8v af = *(const s8v*)&Al[(16 * w + lo) * LDK + ks * 32 + q * 8];
#pragma unroll
        for (int nt = 0; nt < NT; ++nt) {
            s8v wf = *(const s8v*)&Wl[(nt * 16 + lo) * LDK + ks * 32 + q * 8];
            acc[nt] = __builtin_amdgcn_mfma_f32_16x16x32_bf16(wf, af, acc[nt], 0, 0, 0);
        }
    }

    int grow = row0 + 16 * w + lo;
    if (grow < N) {
        float dr = dinv[grow];
        ushort* orow = hs + (size_t)grow * OUTC + q * 4;
#pragma unroll
        for (int nt = 0; nt < NT; ++nt) {
            uint2 p;
            p.x = pack2(acc[nt][0] * dr, acc[nt][1] * dr);
            p.y = pack2(acc[nt][2] * dr, acc[nt][3] * dr);
            *(uint2*)(orow + nt * 16) = p;
        }
    }
}

// ---- aggregation (bf16 gather, f32 accum):
//      out[i] = dinv[i]*(hs[i] + sum_{j in N(i)} hs[j]) + b ----

template <int C, bool RELU, bool OUTBF>
__global__ __launch_bounds__(256) void aggregate_k(const ushort* __restrict__ hs,
                                                   const float* __restrict__ dinv,
                                                   const int* __restrict__ rowptr,
                                                   const int* __restrict__ csr,
                                                   const float* __restrict__ bias,
                                                   void* __restrict__ out, int N) {
    constexpr int LANES = C / 8;       // 16B (8 bf16) per lane
    constexpr int NPB = 256 / LANES;
    int tid = threadIdx.x;
    int sub = tid / LANES;
    int lane = tid % LANES;
    int node = blockIdx.x * NPB + sub;
    if (node >= N) return;

    const uint4* h4 = (const uint4*)hs;
    float accA[8], accB[8];
    {
        uint4 v = h4[(size_t)node * LANES + lane];
        accA[0] = bflo(v.x); accA[1] = bfhi(v.x);
        accA[2] = bflo(v.y); accA[3] = bfhi(v.y);
        accA[4] = bflo(v.z); accA[5] = bfhi(v.z);
        accA[6] = bflo(v.w); accA[7] = bfhi(v.w);
    }
#pragma unroll
    for (int k = 0; k < 8; ++k) accB[k] = 0.f;

    int beg = rowptr[node];
    int end = rowptr[node + 1];
    int e = beg;
    for (; e + 4 <= end; e += 4) {
        int j0 = csr[e + 0];
        int j1 = csr[e + 1];
        int j2 = csr[e + 2];
        int j3 = csr[e + 3];
        uint4 v0 = h4[(size_t)j0 * LANES + lane];
        uint4 v1 = h4[(size_t)j1 * LANES + lane];
        uint4 v2 = h4[(size_t)j2 * LANES + lane];
        uint4 v3 = h4[(size_t)j3 * LANES + lane];
        accA[0] += bflo(v0.x) + bflo(v2.x); accA[1] += bfhi(v0.x) + bfhi(v2.x);
        accA[2] += bflo(v0.y) + bflo(v2.y); accA[3] += bfhi(v0.y) + bfhi(v2.y);
        accA[4] += bflo(v0.z) + bflo(v2.z); accA[5] += bfhi(v0.z) + bfhi(v2.z);
        accA[6] += bflo(v0.w) + bflo(v2.w); accA[7] += bfhi(v0.w) + bfhi(v2.w);
        accB[0] += bflo(v1.x) + bflo(v3.x); accB[1] += bfhi(v1.x) + bfhi(v3.x);
        accB[2] += bflo(v1.y) + bflo(v3.y); accB[3] += bfhi(v1.y) + bfhi(v3.y);
        accB[4] += bflo(v1.z) + bflo(v3.z); accB[5] += bfhi(v1.z) + bfhi(v3.z);
        accB[6] += bflo(v1.w) + bflo(v3.w); accB[7] += bfhi(v1.w) + bfhi(v3.w);
    }
    for (; e < end; ++e) {
        int j = csr[e];
        uint4 v = h4[(size_t)j * LANES + lane];
        accA[0] += bflo(v.x); accA[1] += bfhi(v.x);
        accA[2] += bflo(v.y); accA[3] += bfhi(v.y);
        accA[4] += bflo(v.z); accA[5] += bfhi(v.z);
        accA[6] += bflo(v.w); accA[7] += bfhi(v.w);
    }

    float di = dinv[node];
    const float4* b4 = (const float4*)(bias + lane * 8);
    float4 b0 = b4[0], b1 = b4[1];
    float o[8];
    o[0] = fmaf(di, accA[0] + accB[0], b0.x);
    o[1] = fmaf(di, accA[1] + accB[1], b0.y);
    o[2] = fmaf(di, accA[2] + accB[2], b0.z);
    o[3] = fmaf(di, accA[3] + accB[3], b0.w);
    o[4] = fmaf(di, accA[4] + accB[4], b1.x);
    o[5] = fmaf(di, accA[5] + accB[5], b1.y);
    o[6] = fmaf(di, accA[6] + accB[6], b1.z);
    o[7] = fmaf(di, accA[7] + accB[7], b1.w);
    if (RELU) {
#pragma unroll
        for (int k = 0; k < 8; ++k) o[k] = fmaxf(o[k], 0.f);
    }
    if (OUTBF) {
        uint4 p;
        p.x = pack2(o[0], o[1]);
        p.y = pack2(o[2], o[3]);
        p.z = pack2(o[4], o[5]);
        p.w = pack2(o[6], o[7]);
        ((uint4*)out)[(size_t)node * LANES + lane] = p;
    } else {
        float4* op = (float4*)((float*)out + (size_t)node * C + lane * 8);
        op[0] = make_float4(o[0], o[1], o[2], o[3]);
        op[1] = make_float4(o[4], o[5], o[6], o[7]);
    }
}

// ---------------- launch ----------------

extern "C" void kernel_launch(void* const* d_in, const int* in_sizes, int n_in,
                              void* d_out, int out_size, void* d_ws, size_t ws_size,
                              hipStream_t stream) {
    const float* x  = (const float*)d_in[0];
    const int*   ei = (const int*)d_in[1];
    const float* W1 = (const float*)d_in[2];
    const float* b1 = (const float*)d_in[3];
    const float* W2 = (const float*)d_in[4];
    const float* b2 = (const float*)d_in[5];
    float* out = (float*)d_out;

    const int D = 128;
    int N = in_sizes[0] / D;
    int E = in_sizes[1] / 2;
    const int* src = ei;      // edge_index[0] (sources j)
    const int* dst = ei + E;  // edge_index[1] (targets i)

    char* ws = (char*)d_ws;
    size_t off = 0;
    auto alloc = [&](size_t bytes) -> void* {
        void* p = ws + off;
        off += (bytes + 255) & ~(size_t)255;
        return p;
    };
    int*    cnt   = (int*)alloc((size_t)N * 4);
    float*  dinv  = (float*)alloc((size_t)N * 4);
    int*    rowptr= (int*)alloc((size_t)(N + 1) * 4);
    int*    bsums = (int*)alloc(1024);
    int*    rank  = (int*)alloc((size_t)E * 4);
    int*    csr   = (int*)alloc((size_t)E * 4);
    ushort* wt1   = (ushort*)alloc((size_t)128 * 128 * 2);
    ushort* wt2   = (ushort*)alloc((size_t)64 * 128 * 2);
    ushort* hs1   = (ushort*)alloc((size_t)N * 128 * 2);  // bf16 dinv*(x@W1)
    ushort* h1a   = (ushort*)alloc((size_t)N * 128 * 2);  // layer-1 output (bf16)
    ushort* hs2   = hs1;  // reuse

    int gN = (N + THREADS - 1) / THREADS;
    int half = (E + 1) / 2;
    int gH = (half + THREADS - 1) / THREADS;
    int NB1 = (N + SCAN_CHUNK - 1) / SCAN_CHUNK;

    init_k<<<gN, THREADS, 0, stream>>>(cnt, N);
    rank_k<<<gH, THREADS, 0, stream>>>(dst, E, half, cnt, rank);
    scan1_k<<<NB1, THREADS, 0, stream>>>(cnt, N, bsums);
    scan2_k<<<1, THREADS, 0, stream>>>(bsums, NB1, rowptr, N, E);
    scan3_k<<<NB1, THREADS, 0, stream>>>(cnt, N, bsums, rowptr);
    dinv_k<<<gN, THREADS, 0, stream>>>(cnt, dinv, N);
    scatter2_k<<<gH, THREADS, 0, stream>>>(src, dst, E, half, rowptr, rank, csr);
    wtrans_k<128><<<2, 64, 0, stream>>>(W1, wt1);
    wtrans_k<64><<<1, 64, 0, stream>>>(W2, wt2);

    int gG = (N + 63) / 64;
    // layer 1
    gemm_mfma<128, true><<<gG, 256, 0, stream>>>(x, wt1, dinv, hs1, N);
    aggregate_k<128, true, true><<<(N + 15) / 16, 256, 0, stream>>>(hs1, dinv, rowptr, csr, b1, h1a, N);
    // layer 2
    gemm_mfma<64, false><<<gG, 256, 0, stream>>>(h1a, wt2, dinv, hs2, N);
    aggregate_k<64, false, false><<<(N + 31) / 32, 256, 0, stream>>>(hs2, dinv, rowptr, csr, b2, out, N);
}

// Round 6
// 205.004 us; speedup vs baseline: 2.4562x; 1.2374x over previous
//
#include <hip/hip_runtime.h>

typedef unsigned int uint;
typedef unsigned short ushort;
typedef short s8v __attribute__((ext_vector_type(8)));   // 8 bf16 (4 VGPRs)
typedef float f4v __attribute__((ext_vector_type(4)));   // 4 f32 acc

#define BSHIFT 8                 // 256 nodes per bucket
#define NBUCK_MAX 512
#define PART_CH 4096             // edges per partition block

// ---------------- bf16 helpers ----------------

__device__ __forceinline__ uint f2bf(float f) {       // RNE round to bf16, low 16
    uint b = __float_as_uint(f);
    return (b + 0x7fffu + ((b >> 16) & 1u)) >> 16;
}
__device__ __forceinline__ uint pack2(float a, float b) {
    return f2bf(a) | (f2bf(b) << 16);
}
__device__ __forceinline__ float bflo(uint u) { return __uint_as_float(u << 16); }
__device__ __forceinline__ float bfhi(uint u) { return __uint_as_float(u & 0xffff0000u); }

// ---------------- bucketed CSR build (no per-edge global atomics) ----------------
// bucket b = dst >> 8 (256 nodes per bucket). eb[] holds edges partitioned by
// bucket, packed as (src << 8) | (dst & 255).  src < 2^17 so this fits 25 bits.

__global__ __launch_bounds__(256) void hist_k(const int* __restrict__ dst, int E, int nbuck,
                                              int* __restrict__ bcnt) {
    __shared__ int h[NBUCK_MAX];
    int t = threadIdx.x;
    for (int i = t; i < nbuck; i += 256) h[i] = 0;
    __syncthreads();
    int e0 = blockIdx.x * PART_CH;
    int e1 = min(e0 + PART_CH, E);
    for (int e = e0 + t; e < e1; e += 256) atomicAdd(&h[((uint)dst[e]) >> BSHIFT], 1);
    __syncthreads();
    for (int i = t; i < nbuck; i += 256) {
        int v = h[i];
        if (v) atomicAdd(&bcnt[i], v);
    }
}

__global__ __launch_bounds__(512) void bscan_k(const int* __restrict__ bcnt, int nbuck, int E,
                                               int* __restrict__ bo, int* __restrict__ bcur) {
    __shared__ int s[512];
    int t = threadIdx.x;
    int v = (t < nbuck) ? bcnt[t] : 0;
    s[t] = v;
    __syncthreads();
    for (int off = 1; off < 512; off <<= 1) {
        int x = (t >= off) ? s[t - off] : 0;
        __syncthreads();
        s[t] += x;
        __syncthreads();
    }
    int excl = s[t] - v;
    if (t < nbuck) { bo[t] = excl; bcur[t] = excl; }
    if (t == 0) bo[nbuck] = E;
}

__global__ __launch_bounds__(256) void part_k(const int* __restrict__ src,
                                              const int* __restrict__ dst, int E, int nbuck,
                                              int* __restrict__ bcur, uint* __restrict__ eb) {
    __shared__ int h[NBUCK_MAX];
    __shared__ int cur[NBUCK_MAX];
    int t = threadIdx.x;
    for (int i = t; i < nbuck; i += 256) h[i] = 0;
    __syncthreads();
    int e0 = blockIdx.x * PART_CH;
    int e1 = min(e0 + PART_CH, E);
    for (int e = e0 + t; e < e1; e += 256) atomicAdd(&h[((uint)dst[e]) >> BSHIFT], 1);
    __syncthreads();
    // reserve disjoint global ranges per (block, bucket)
    for (int i = t; i < nbuck; i += 256) {
        int v = h[i];
        cur[i] = v ? atomicAdd(&bcur[i], v) : 0;
    }
    __syncthreads();
    for (int e = e0 + t; e < e1; e += 256) {
        int d = dst[e];
        int b = ((uint)d) >> BSHIFT;
        int p = atomicAdd(&cur[b], 1);           // LDS atomic: cheap
        eb[p] = ((uint)src[e] << BSHIFT) | (uint)(d & 255);
    }
}

// one block per bucket: exact per-node counts, rowptr, dinv, and CSR fill
__global__ __launch_bounds__(256) void build_k(const uint* __restrict__ eb,
                                               const int* __restrict__ bo, int N, int E,
                                               int* __restrict__ rowptr,
                                               float* __restrict__ dinv,
                                               int* __restrict__ csr) {
    __shared__ int c[256];
    __shared__ int s[256];
    int b = blockIdx.x;
    int t = threadIdx.x;
    int node0 = b << BSHIFT;
    int beg = bo[b], end = bo[b + 1];
    c[t] = 0;
    __syncthreads();
    for (int e = beg + t; e < end; e += 256) atomicAdd(&c[eb[e] & 255], 1);
    __syncthreads();
    int v = c[t];
    s[t] = v;
    __syncthreads();
    for (int off = 1; off < 256; off <<= 1) {
        int x = (t >= off) ? s[t - off] : 0;
        __syncthreads();
        s[t] += x;
        __syncthreads();
    }
    int excl = s[t] - v;
    int node = node0 + t;
    if (node < N) {
        rowptr[node] = beg + excl;
        dinv[node] = rsqrtf((float)(1 + v));
    }
    if (b == 0 && t == 0) rowptr[N] = E;
    __syncthreads();
    c[t] = beg + excl;                 // reuse as absolute cursor per node
    __syncthreads();
    for (int e = beg + t; e < end; e += 256) {
        uint pk = eb[e];
        int p = atomicAdd(&c[pk & 255], 1);    // LDS atomic
        csr[p] = (int)(pk >> BSHIFT);
    }
}

// ---------------- W transpose+convert: W[128][OUTC] f32 -> Wt[OUTC][128] bf16 ----------------

template <int OUTC>
__global__ void wtrans_k(const float* __restrict__ W, ushort* __restrict__ Wt) {
    int c = blockIdx.x * 64 + threadIdx.x;
    if (c >= OUTC) return;
    for (int k0 = 0; k0 < 128; k0 += 8) {
        float v[8];
#pragma unroll
        for (int i = 0; i < 8; ++i) v[i] = W[(size_t)(k0 + i) * OUTC + c];
        uint4 p;
        p.x = pack2(v[0], v[1]);
        p.y = pack2(v[2], v[3]);
        p.z = pack2(v[4], v[5]);
        p.w = pack2(v[6], v[7]);
        *(uint4*)(Wt + (size_t)c * 128 + k0) = p;
    }
}

// ---------------- MFMA GEMM: hs[N x OUTC](bf16) = dinv[row] * (A[N x 128] @ W) ----------------

template <int OUTC, bool AF32>
__global__ __launch_bounds__(256) void gemm_mfma(const void* __restrict__ Ain,
                                                 const ushort* __restrict__ Wt,
                                                 const float* __restrict__ dinv,
                                                 ushort* __restrict__ hs, int N) {
    constexpr int NT = OUTC / 16;
    constexpr int LDK = 136;
    __shared__ ushort Al[64 * LDK];
    __shared__ ushort Wl[OUTC * LDK];

    int tid = threadIdx.x;
    int row0 = blockIdx.x * 64;

    {
        int r = tid >> 2, seg = tid & 3;
        int gr = row0 + r;
        if (gr > N - 1) gr = N - 1;
        ushort* dstp = &Al[r * LDK + seg * 32];
        if (AF32) {
            const float4* ap = (const float4*)((const float*)Ain + (size_t)gr * 128 + seg * 32);
#pragma unroll
            for (int i = 0; i < 4; ++i) {
                float4 f0 = ap[2 * i], f1 = ap[2 * i + 1];
                uint4 u;
                u.x = pack2(f0.x, f0.y);
                u.y = pack2(f0.z, f0.w);
                u.z = pack2(f1.x, f1.y);
                u.w = pack2(f1.z, f1.w);
                *(uint4*)(dstp + i * 8) = u;
            }
        } else {
            const uint4* ap = (const uint4*)((const ushort*)Ain + (size_t)gr * 128 + seg * 32);
#pragma unroll
            for (int i = 0; i < 4; ++i) *(uint4*)(dstp + i * 8) = ap[i];
        }
    }
    {
        const uint4* wp = (const uint4*)Wt;
        for (int idx = tid; idx < OUTC * 16; idx += 256) {
            int r = idx >> 4, c = idx & 15;
            *(uint4*)(&Wl[r * LDK + c * 8]) = wp[idx];
        }
    }
    __syncthreads();

    int w = tid >> 6;
    int l = tid & 63;
    int lo = l & 15, q = l >> 4;

    f4v acc[NT];
#pragma unroll
    for (int i = 0; i < NT; ++i) acc[i] = (f4v){0.f, 0.f, 0.f, 0.f};

#pragma unroll
    for (int ks = 0; ks < 4; ++ks) {
        s8v af = *(const s8v*)&Al[(16 * w + lo) * LDK + ks * 32 + q * 8];
#pragma unroll
        for (int nt = 0; nt < NT; ++nt) {
            s8v wf = *(const s8v*)&Wl[(nt * 16 + lo) * LDK + ks * 32 + q * 8];
            acc[nt] = __builtin_amdgcn_mfma_f32_16x16x32_bf16(wf, af, acc[nt], 0, 0, 0);
        }
    }

    int grow = row0 + 16 * w + lo;
    if (grow < N) {
        float dr = dinv[grow];
        ushort* orow = hs + (size_t)grow * OUTC + q * 4;
#pragma unroll
        for (int nt = 0; nt < NT; ++nt) {
            uint2 p;
            p.x = pack2(acc[nt][0] * dr, acc[nt][1] * dr);
            p.y = pack2(acc[nt][2] * dr, acc[nt][3] * dr);
            *(uint2*)(orow + nt * 16) = p;
        }
    }
}

// ---- aggregation (bf16 gather, f32 accum, 8-deep pipelined):
//      out[i] = dinv[i]*(hs[i] + sum_{j in N(i)} hs[j]) + b ----

template <int C, bool RELU, bool OUTBF>
__global__ __launch_bounds__(256) void aggregate_k(const ushort* __restrict__ hs,
                                                   const float* __restrict__ dinv,
                                                   const int* __restrict__ rowptr,
                                                   const int* __restrict__ csr,
                                                   const float* __restrict__ bias,
                                                   void* __restrict__ out, int N) {
    constexpr int LANES = C / 8;       // 16B (8 bf16) per lane
    constexpr int NPB = 256 / LANES;
    int tid = threadIdx.x;
    int sub = tid / LANES;
    int lane = tid % LANES;
    int node = blockIdx.x * NPB + sub;
    if (node >= N) return;

    const uint4* h4 = (const uint4*)hs;
    float accA[8], accB[8];
    {
        uint4 v = h4[(size_t)node * LANES + lane];
        accA[0] = bflo(v.x); accA[1] = bfhi(v.x);
        accA[2] = bflo(v.y); accA[3] = bfhi(v.y);
        accA[4] = bflo(v.z); accA[5] = bfhi(v.z);
        accA[6] = bflo(v.w); accA[7] = bfhi(v.w);
    }
#pragma unroll
    for (int k = 0; k < 8; ++k) accB[k] = 0.f;

    int beg = rowptr[node];
    int end = rowptr[node + 1];
    int e = beg;
    for (; e + 8 <= end; e += 8) {
        int j[8];
#pragma unroll
        for (int k = 0; k < 8; ++k) j[k] = csr[e + k];
        uint4 v[8];
#pragma unroll
        for (int k = 0; k < 8; ++k) v[k] = h4[(size_t)j[k] * LANES + lane];
#pragma unroll
        for (int k = 0; k < 8; ++k) {
            float* a = (k & 1) ? accB : accA;   // k static -> folds at compile time
            a[0] += bflo(v[k].x); a[1] += bfhi(v[k].x);
            a[2] += bflo(v[k].y); a[3] += bfhi(v[k].y);
            a[4] += bflo(v[k].z); a[5] += bfhi(v[k].z);
            a[6] += bflo(v[k].w); a[7] += bfhi(v[k].w);
        }
    }
    if (e + 4 <= end) {
        int j0 = csr[e + 0];
        int j1 = csr[e + 1];
        int j2 = csr[e + 2];
        int j3 = csr[e + 3];
        uint4 v0 = h4[(size_t)j0 * LANES + lane];
        uint4 v1 = h4[(size_t)j1 * LANES + lane];
        uint4 v2 = h4[(size_t)j2 * LANES + lane];
        uint4 v3 = h4[(size_t)j3 * LANES + lane];
        accA[0] += bflo(v0.x) + bflo(v2.x); accA[1] += bfhi(v0.x) + bfhi(v2.x);
        accA[2] += bflo(v0.y) + bflo(v2.y); accA[3] += bfhi(v0.y) + bfhi(v2.y);
        accA[4] += bflo(v0.z) + bflo(v2.z); accA[5] += bfhi(v0.z) + bfhi(v2.z);
        accA[6] += bflo(v0.w) + bflo(v2.w); accA[7] += bfhi(v0.w) + bfhi(v2.w);
        accB[0] += bflo(v1.x) + bflo(v3.x); accB[1] += bfhi(v1.x) + bfhi(v3.x);
        accB[2] += bflo(v1.y) + bflo(v3.y); accB[3] += bfhi(v1.y) + bfhi(v3.y);
        accB[4] += bflo(v1.z) + bflo(v3.z); accB[5] += bfhi(v1.z) + bfhi(v3.z);
        accB[6] += bflo(v1.w) + bflo(v3.w); accB[7] += bfhi(v1.w) + bfhi(v3.w);
        e += 4;
    }
    for (; e < end; ++e) {
        int j = csr[e];
        uint4 v = h4[(size_t)j * LANES + lane];
        accA[0] += bflo(v.x); accA[1] += bfhi(v.x);
        accA[2] += bflo(v.y); accA[3] += bfhi(v.y);
        accA[4] += bflo(v.z); accA[5] += bfhi(v.z);
        accA[6] += bflo(v.w); accA[7] += bfhi(v.w);
    }

    float di = dinv[node];
    const float4* b4 = (const float4*)(bias + lane * 8);
    float4 b0 = b4[0], b1 = b4[1];
    float o[8];
    o[0] = fmaf(di, accA[0] + accB[0], b0.x);
    o[1] = fmaf(di, accA[1] + accB[1], b0.y);
    o[2] = fmaf(di, accA[2] + accB[2], b0.z);
    o[3] = fmaf(di, accA[3] + accB[3], b0.w);
    o[4] = fmaf(di, accA[4] + accB[4], b1.x);
    o[5] = fmaf(di, accA[5] + accB[5], b1.y);
    o[6] = fmaf(di, accA[6] + accB[6], b1.z);
    o[7] = fmaf(di, accA[7] + accB[7], b1.w);
    if (RELU) {
#pragma unroll
        for (int k = 0; k < 8; ++k) o[k] = fmaxf(o[k], 0.f);
    }
    if (OUTBF) {
        uint4 p;
        p.x = pack2(o[0], o[1]);
        p.y = pack2(o[2], o[3]);
        p.z = pack2(o[4], o[5]);
        p.w = pack2(o[6], o[7]);
        ((uint4*)out)[(size_t)node * LANES + lane] = p;
    } else {
        float4* op = (float4*)((float*)out + (size_t)node * C + lane * 8);
        op[0] = make_float4(o[0], o[1], o[2], o[3]);
        op[1] = make_float4(o[4], o[5], o[6], o[7]);
    }
}

// ---------------- launch ----------------

extern "C" void kernel_launch(void* const* d_in, const int* in_sizes, int n_in,
                              void* d_out, int out_size, void* d_ws, size_t ws_size,
                              hipStream_t stream) {
    const float* x  = (const float*)d_in[0];
    const int*   ei = (const int*)d_in[1];
    const float* W1 = (const float*)d_in[2];
    const float* b1 = (const float*)d_in[3];
    const float* W2 = (const float*)d_in[4];
    const float* b2 = (const float*)d_in[5];
    float* out = (float*)d_out;

    const int D = 128;
    int N = in_sizes[0] / D;
    int E = in_sizes[1] / 2;
    const int* src = ei;      // edge_index[0] (sources j)
    const int* dst = ei + E;  // edge_index[1] (targets i)

    int nbuck = (N + 255) >> BSHIFT;   // 256 nodes per bucket (<= NBUCK_MAX for N<=131072)

    char* ws = (char*)d_ws;
    size_t off = 0;
    auto alloc = [&](size_t bytes) -> void* {
        void* p = ws + off;
        off += (bytes + 255) & ~(size_t)255;
        return p;
    };
    int*    bcnt  = (int*)alloc((size_t)NBUCK_MAX * 4);
    int*    bo    = (int*)alloc((size_t)(NBUCK_MAX + 1) * 4);
    int*    bcur  = (int*)alloc((size_t)NBUCK_MAX * 4);
    int*    rowptr= (int*)alloc((size_t)(N + 1) * 4);
    float*  dinv  = (float*)alloc((size_t)N * 4);
    uint*   eb    = (uint*)alloc((size_t)E * 4);
    int*    csr   = (int*)alloc((size_t)E * 4);
    ushort* wt1   = (ushort*)alloc((size_t)128 * 128 * 2);
    ushort* wt2   = (ushort*)alloc((size_t)64 * 128 * 2);
    ushort* hs1   = (ushort*)alloc((size_t)N * 128 * 2);  // bf16 dinv*(x@W1)
    ushort* h1a   = (ushort*)alloc((size_t)N * 128 * 2);  // layer-1 output (bf16)
    ushort* hs2   = hs1;  // reuse

    int PB = (E + PART_CH - 1) / PART_CH;

    hipMemsetAsync(bcnt, 0, (size_t)NBUCK_MAX * 4, stream);
    hist_k<<<PB, 256, 0, stream>>>(dst, E, nbuck, bcnt);
    bscan_k<<<1, 512, 0, stream>>>(bcnt, nbuck, E, bo, bcur);
    part_k<<<PB, 256, 0, stream>>>(src, dst, E, nbuck, bcur, eb);
    build_k<<<nbuck, 256, 0, stream>>>(eb, bo, N, E, rowptr, dinv, csr);
    wtrans_k<128><<<2, 64, 0, stream>>>(W1, wt1);
    wtrans_k<64><<<1, 64, 0, stream>>>(W2, wt2);

    int gG = (N + 63) / 64;
    // layer 1
    gemm_mfma<128, true><<<gG, 256, 0, stream>>>(x, wt1, dinv, hs1, N);
    aggregate_k<128, true, true><<<(N + 15) / 16, 256, 0, stream>>>(hs1, dinv, rowptr, csr, b1, h1a, N);
    // layer 2
    gemm_mfma<64, false><<<gG, 256, 0, stream>>>(h1a, wt2, dinv, hs2, N);
    aggregate_k<64, false, false><<<(N + 31) / 32, 256, 0, stream>>>(hs2, dinv, rowptr, csr, b2, out, N);
}